// Round 6
// baseline (179.742 us; speedup 1.0000x reference)
//
#include <hip/hip_runtime.h>

// SSIM loss, fused separable Gaussian (11x11, sigma=1.5) over [32,3,512,512] f32.
// R6: async global_load_lds staging (width=16) of raw tiles -> LDS; both FIR
//     passes run from LDS. Kills the 28-serialized-VMEM-latency chain that
//     pinned R2-R5 at ~172 us (compiler allocated 36 VGPR and couldn't batch
//     loads; global_load_lds needs no data VGPRs and drains once per tile).
//     Raw staged as flat 264-float rows (66 lanes x 16B), wave-contiguous
//     lane order (linear-dest rule). 320-thread block: V-FIR's 266 cols in
//     one pass. Borders: clamped source rows + uniform masks (no OOB loads).

typedef float f32x2 __attribute__((ext_vector_type(2)));
typedef unsigned int u32;

#define IH 512
#define IW 512
#define TH 4                 // output rows per tile
#define TW 256               // output cols per tile
#define PW 266               // TW + 10 FIR cols
#define RRN 14               // raw rows per tile
#define SW 264               // staged floats per row-img (66 x 4)
#define NRI (RRN * 2)        // 28 row-imgs (p,t interleaved)
#define NTHR 320
#define NITER 6              // ceil(28*66 / 320) staging iterations
#define PADSL (NITER * NTHR) // 1920 lane-slots (72 pad slots, written not read)
#define LPW 268              // intermediate row stride in f32x2
#define HTILES 128
#define WTILES 2
#define NBLK (96 * HTILES * WTILES)  // 24576
#define NBINS 64
#define NPIX 25165824.0f     // 96*512*512

constexpr float GW[11] = {
    0.00102838f, 0.00759877f, 0.03600078f, 0.10936070f, 0.21300554f,
    0.26601173f,
    0.21300554f, 0.10936070f, 0.03600078f, 0.00759877f, 0.00102838f
};
constexpr float C1f = 0.0001f;  // 0.01^2
constexpr float C2f = 0.0009f;  // 0.03^2

__global__ void ssim_zero(float* ws) { ws[threadIdx.x] = 0.0f; }

__global__ void ssim_fin(const float* __restrict__ ws, float* __restrict__ out) {
    float v = ws[threadIdx.x];
    #pragma unroll
    for (int off = 32; off > 0; off >>= 1) v += __shfl_down(v, off, 64);
    if (threadIdx.x == 0) out[0] = 1.0f - v * (1.0f / NPIX);
}

// Vertical FIR over one column from staged LDS raw rows.
// chains packed cross-signal: a01=(E[p],E[t]), a23=(E[p^2+t^2],E[p*t]).
template<bool BORDER>
__device__ __forceinline__ void fir_col(const float* __restrict__ raw, int lc,
                                        int rbase, f32x2 a01[TH], f32x2 a23[TH])
{
    #pragma unroll
    for (int rr = 0; rr < RRN; ++rr) {
        float p = raw[(2 * rr) * SW + lc];
        float t = raw[(2 * rr + 1) * SW + lc];
        if (BORDER) {
            const float rm = ((unsigned)(rbase + rr) < (unsigned)IH) ? 1.0f : 0.0f;
            p *= rm; t *= rm;
        }
        f32x2 s01; s01.x = p; s01.y = t;
        f32x2 s23; s23.x = fmaf(p, p, t * t); s23.y = p * t;
        #pragma unroll
        for (int ro = 0; ro < TH; ++ro) {
            const int k = rr - ro;          // compile-time after unroll
            if (k >= 0 && k < 11) {
                const f32x2 g = {GW[k], GW[k]};
                a01[ro] = __builtin_elementwise_fma(g, s01, a01[ro]);
                a23[ro] = __builtin_elementwise_fma(g, s23, a23[ro]);
            }
        }
    }
}

__global__ __launch_bounds__(NTHR, 4) void ssim_main(
    const float* __restrict__ pred,
    const float* __restrict__ targ,
    float* __restrict__ ws)
{
    __shared__ __align__(16) float raw[PADSL * 4];      // 30720 B
    __shared__ __align__(16) f32x2 lds01[TH][LPW];      // (E[p], E[t])
    __shared__ __align__(16) f32x2 lds23[TH][LPW];      // (E[p^2+t^2], E[p*t])
    __shared__ float wsum[5];

    const int tid = threadIdx.x;
    const int bid = blockIdx.x;
    const int wt = bid & (WTILES - 1);
    const int ht = (bid >> 1) & (HTILES - 1);
    const int bc = bid >> 8;
    const int h0 = ht * TH;
    const int w0 = wt * TW;
    const int rbase = h0 - 5;
    const int src0 = wt ? 248 : 0;      // staged col c <-> global col src0+c
    const float* __restrict__ P = pred + (size_t)bc * (IH * IW);
    const float* __restrict__ T = targ + (size_t)bc * (IH * IW);

    // ---------------- Stage: async global -> LDS (no data VGPRs) ----------
    #pragma unroll
    for (int i = 0; i < NITER; ++i) {
        const u32 u = (u32)tid + (u32)(i * NTHR);   // flat 16B lane-slot
        const u32 r = u / 66u;                      // row-img 0..29 (28,29 pad)
        const u32 l = u - r * 66u;                  // lane within row-img
        const u32 rc = r < 27u ? r : 27u;           // clamp pad slots
        const int row = (int)(rc >> 1);
        const int img = (int)(rc & 1u);
        int hr = rbase + row;                       // clamped: loads stay
        hr = hr < 0 ? 0 : (hr > IH - 1 ? IH - 1 : hr);  // in-bounds; masked later
        const float* gsrc = (img ? T : P) + hr * IW + src0 + (l << 2);
        __builtin_amdgcn_global_load_lds(
            (const __attribute__((address_space(1))) u32*)gsrc,
            (__attribute__((address_space(3))) u32*)&raw[(size_t)u * 4],
            16, 0, 0);
    }
    __syncthreads();   // drains vmcnt before any wave crosses

    // ---------------- Phase 1: vertical FIR from LDS ----------------------
    const bool vint = (rbase >= 0) && (rbase + RRN <= IH);
    const int cc = tid;
    if (cc < PW) {
        const int w = w0 - 5 + cc;
        const float wm = ((unsigned)w < (unsigned)IW) ? 1.0f : 0.0f;
        int lc = w - src0;
        lc = lc < 0 ? 0 : (lc > SW - 1 ? SW - 1 : lc);

        f32x2 a01[TH], a23[TH];
        #pragma unroll
        for (int ro = 0; ro < TH; ++ro) {
            a01[ro].x = 0.f; a01[ro].y = 0.f;
            a23[ro].x = 0.f; a23[ro].y = 0.f;
        }

        if (vint) fir_col<false>(raw, lc, rbase, a01, a23);
        else      fir_col<true >(raw, lc, rbase, a01, a23);

        const f32x2 wmv = {wm, wm};
        #pragma unroll
        for (int ro = 0; ro < TH; ++ro) {
            lds01[ro][cc] = a01[ro] * wmv;
            lds23[ro][cc] = a23[ro] * wmv;
        }
    }
    __syncthreads();

    // ---------------- Phase 2: horizontal conv + SSIM epilogue ------------
    float lsum = 0.0f;
    if (tid < 256) {
        const int r  = tid >> 6;            // 0..3
        const int c0 = (tid & 63) << 2;     // 0..252

        // taps c0..c0+13 (f32x2) -> 7 aligned float4 loads per stat pair
        float4 u4[7], v4[7];
        {
            const float4* b01 = reinterpret_cast<const float4*>(&lds01[r][c0]);
            const float4* b23 = reinterpret_cast<const float4*>(&lds23[r][c0]);
            #pragma unroll
            for (int q = 0; q < 7; ++q) { u4[q] = b01[q]; v4[q] = b23[q]; }
        }
        const f32x2* x01 = reinterpret_cast<const f32x2*>(u4);   // 14 elems
        const f32x2* x23 = reinterpret_cast<const f32x2*>(v4);

        #pragma unroll
        for (int j = 0; j < 4; ++j) {
            f32x2 acc01; acc01.x = 0.f; acc01.y = 0.f;
            f32x2 acc23; acc23.x = 0.f; acc23.y = 0.f;
            #pragma unroll
            for (int k = 0; k < 11; ++k) {
                const f32x2 g = {GW[k], GW[k]};
                acc01 = __builtin_elementwise_fma(g, x01[j + k], acc01);
                acc23 = __builtin_elementwise_fma(g, x23[j + k], acc23);
            }
            const float m1  = acc01.x;
            const float m2  = acc01.y;
            const float sPP = acc23.x;      // E[p^2]+E[t^2]
            const float e12 = acc23.y;      // E[p*t]
            const float m1m2 = m1 * m2;
            const float msq  = fmaf(m1, m1, m2 * m2);
            const float num = fmaf(2.0f, m1m2, C1f) * fmaf(2.0f, (e12 - m1m2), C2f);
            const float den = (msq + C1f) * ((sPP - msq) + C2f);
            lsum = fmaf(num, __builtin_amdgcn_rcpf(den), lsum);
        }
    }

    // ---------------- Reduction: wave shuffle -> LDS -> binned atomic -----
    #pragma unroll
    for (int off = 32; off > 0; off >>= 1) {
        lsum += __shfl_down(lsum, off, 64);
    }
    const int lane = tid & 63;
    const int wv   = tid >> 6;              // 0..4
    if (lane == 0) wsum[wv] = lsum;
    __syncthreads();
    if (tid == 0) {
        const float bs = wsum[0] + wsum[1] + wsum[2] + wsum[3] + wsum[4];
        atomicAdd(&ws[bid & (NBINS - 1)], bs);
    }
}

extern "C" void kernel_launch(void* const* d_in, const int* in_sizes, int n_in,
                              void* d_out, int out_size, void* d_ws, size_t ws_size,
                              hipStream_t stream) {
    const float* pred = (const float*)d_in[0];
    const float* targ = (const float*)d_in[1];
    float* out = (float*)d_out;
    float* wsf = (float*)d_ws;

    hipLaunchKernelGGL(ssim_zero, dim3(1), dim3(NBINS), 0, stream, wsf);
    hipLaunchKernelGGL(ssim_main, dim3(NBLK), dim3(NTHR), 0, stream, pred, targ, wsf);
    hipLaunchKernelGGL(ssim_fin, dim3(1), dim3(64), 0, stream, wsf, out);
}

// Round 7
// 178.559 us; speedup vs baseline: 1.0066x; 1.0066x over previous
//
#include <hip/hip_runtime.h>

// SSIM loss, fused separable Gaussian (11x11, sigma=1.5) over [32,3,512,512] f32.
// R7: pipelined ring-slab. Block owns 16 vertically-consecutive 4x256 tiles of
//     one channel-image half. Raw rows live in an LDS ring of 6 groups
//     (group = 4 rows x {p,t} x 264 floats, padded to 10240 B). Per tile:
//       1. issue gload_lds prefetch of group j+3 (affine flat-u dest)
//       2. V-FIR from LDS ring (ds_read_b32, stride-1) -> stats LDS
//       3. __syncthreads (drains prefetch UNDER compute + stats visible)
//       4. H-pass + SSIM epilogue -> per-thread lsum (across tiles)
//       5. __syncthreads
//     Kills the per-tile fetch-latency chain (R2-R6 pinned ~172-195 us) and
//     cuts vertical re-fetch: 14 rows/tile staged -> 4 (fetch 3.5x -> 1.25x).

typedef float f32x2 __attribute__((ext_vector_type(2)));
typedef unsigned int u32;

#define IH 512
#define IW 512
#define TW 256
#define PW 266               // TW + 10 FIR cols
#define SW 264               // staged floats per row-img (66 x 16B)
#define RPF 528              // floats per row-pair (p row + t row)
#define GSF 2560             // floats per group-slot (2112 used + pad, 10240 B)
#define NSLOT 6              // ring of 6 four-row groups
#define KT 16                // tiles per block
#define NSLAB 8              // 128 ht-tiles / KT
#define NBLK (96 * 2 * NSLAB) // 1536
#define LPW 268              // stats row stride in f32x2
#define NBINS 64
#define NPIX 25165824.0f     // 96*512*512
#define NTHR 320

constexpr float GW[11] = {
    0.00102838f, 0.00759877f, 0.03600078f, 0.10936070f, 0.21300554f,
    0.26601173f,
    0.21300554f, 0.10936070f, 0.03600078f, 0.00759877f, 0.00102838f
};
constexpr float C1f = 0.0001f;  // 0.01^2
constexpr float C2f = 0.0009f;  // 0.03^2

__global__ void ssim_zero(float* ws) { ws[threadIdx.x] = 0.0f; }

__global__ void ssim_fin(const float* __restrict__ ws, float* __restrict__ out) {
    float v = ws[threadIdx.x];
    #pragma unroll
    for (int off = 32; off > 0; off >>= 1) v += __shfl_down(v, off, 64);
    if (threadIdx.x == 0) out[0] = 1.0f - v * (1.0f / NPIX);
}

// Stage group m (rows 4m..4m+3 clamped, p+t) into ring slot `slot`.
// Dest is flat u*16B from the slot base -> affine per wave (linear-dest rule).
// u in [0,640): 528 real lane-slots + 112 pad (written into slot pad region).
__device__ __forceinline__ void stage_group(const float* __restrict__ P,
                                            const float* __restrict__ T,
                                            float* __restrict__ rawp,
                                            int slot, int m, int src0, int tid)
{
    #pragma unroll
    for (int it = 0; it < 2; ++it) {
        const u32 u  = (u32)tid + (u32)(it * NTHR);
        const u32 ue = u > 527u ? 527u : u;
        const u32 ri  = ue / 132u;               // row-in-group 0..3
        const u32 rem = ue - ri * 132u;
        const u32 img = rem >= 66u ? 1u : 0u;
        const u32 l   = rem - (img ? 66u : 0u);  // 16B lane within row-img
        int rowg = 4 * m + (int)ri;
        rowg = rowg < 0 ? 0 : (rowg > IH - 1 ? IH - 1 : rowg);
        const float* gsrc = (img ? T : P) + rowg * IW + src0 + (int)(l << 2);
        float* ldst = rawp + slot * GSF + (int)u * 4;
        __builtin_amdgcn_global_load_lds(
            (const __attribute__((address_space(1))) u32*)gsrc,
            (__attribute__((address_space(3))) u32*)ldst, 16, 0, 0);
    }
}

__global__ __launch_bounds__(NTHR, 2) void ssim_main(
    const float* __restrict__ pred,
    const float* __restrict__ targ,
    float* __restrict__ ws)
{
    __shared__ __align__(16) float raw[NSLOT * GSF];     // 61440 B ring
    __shared__ __align__(16) f32x2 lds01[4][LPW];        // (E[p], E[t])
    __shared__ __align__(16) f32x2 lds23[4][LPW];        // (E[p^2+t^2], E[p*t])
    __shared__ float wsum[5];

    const int tid   = threadIdx.x;
    const int bid   = blockIdx.x;
    const int wt    = bid & 1;
    const int bslab = (bid >> 1) & (NSLAB - 1);
    const int bc    = bid >> 4;
    const int w0    = wt * TW;
    const int src0  = wt ? 248 : 0;        // staged col c <-> global col src0+c
    const int j0    = bslab * KT;          // first ht tile of this block
    const float* __restrict__ P = pred + (size_t)bc * (IH * IW);
    const float* __restrict__ T = targ + (size_t)bc * (IH * IW);

    // per-thread column precompute (V-phase)
    const int w  = w0 - 5 + tid;                       // FIR col (tid < PW)
    const float wm = ((unsigned)w < (unsigned)IW) ? 1.0f : 0.0f;
    int lc = w - src0;
    lc = lc < 0 ? 0 : (lc > SW - 1 ? SW - 1 : lc);

    // ---------------- Prologue: stage groups j0-2 .. j0+2 ------------------
    #pragma unroll
    for (int g = 0; g < 5; ++g) {
        const int m = j0 - 2 + g;
        stage_group(P, T, raw, (m + 12) % NSLOT, m, src0, tid);
    }
    __syncthreads();

    float lsum = 0.0f;
    int jm = (j0 + 4) % NSLOT;             // slot of group (j-2) for j=j0

    for (int jj = 0; jj < KT; ++jj) {
        const int j = j0 + jj;

        // ---- 1. prefetch group j+3 (slot (jm+5)%6), hidden under compute --
        if (jj <= KT - 2) {
            int ps = jm + 5; ps = ps >= NSLOT ? ps - NSLOT : ps;
            stage_group(P, T, raw, ps, j + 3, src0, tid);
        }

        // ---- 2. V-phase: vertical FIR from LDS ring -> stats LDS ----------
        if (tid < PW) {
            int slots5[5];
            #pragma unroll
            for (int d = 0; d < 5; ++d) {
                int s = jm + d; slots5[d] = s >= NSLOT ? s - NSLOT : s;
            }
            const bool border = (j <= 1) || (j >= 126);

            f32x2 a01[4], a23[4];
            #pragma unroll
            for (int ro = 0; ro < 4; ++ro) {
                a01[ro].x = 0.f; a01[ro].y = 0.f;
                a23[ro].x = 0.f; a23[ro].y = 0.f;
            }
            #pragma unroll
            for (int rr = 0; rr < 14; ++rr) {
                const int dm  = (rr + 3) >> 2;     // 0..4 static
                const int rig = (rr + 3) & 3;      // static
                const float* pp = &raw[slots5[dm] * GSF + rig * RPF + lc];
                float p = pp[0];
                float t = pp[SW];
                if (border) {
                    const int r = 4 * j - 5 + rr;
                    const float rm = ((unsigned)r < (unsigned)IH) ? 1.0f : 0.0f;
                    p *= rm; t *= rm;
                }
                f32x2 s01; s01.x = p; s01.y = t;
                f32x2 s23; s23.x = fmaf(p, p, t * t); s23.y = p * t;
                #pragma unroll
                for (int ro = 0; ro < 4; ++ro) {
                    const int k = rr - ro;         // static after unroll
                    if (k >= 0 && k < 11) {
                        const f32x2 g = {GW[k], GW[k]};
                        a01[ro] = __builtin_elementwise_fma(g, s01, a01[ro]);
                        a23[ro] = __builtin_elementwise_fma(g, s23, a23[ro]);
                    }
                }
            }
            const f32x2 wmv = {wm, wm};
            #pragma unroll
            for (int ro = 0; ro < 4; ++ro) {
                lds01[ro][tid] = a01[ro] * wmv;
                lds23[ro][tid] = a23[ro] * wmv;
            }
        }
        __syncthreads();   // stats visible; prefetch drained (under compute)

        // ---- 3. H-phase: horizontal conv + SSIM epilogue ------------------
        if (tid < 256) {
            const int r  = tid >> 6;            // 0..3
            const int c0 = (tid & 63) << 2;     // 0..252

            float4 u4[7], v4[7];
            const float4* b01 = reinterpret_cast<const float4*>(&lds01[r][c0]);
            const float4* b23 = reinterpret_cast<const float4*>(&lds23[r][c0]);
            #pragma unroll
            for (int q = 0; q < 7; ++q) { u4[q] = b01[q]; v4[q] = b23[q]; }
            const f32x2* x01 = reinterpret_cast<const f32x2*>(u4);   // 14 elems
            const f32x2* x23 = reinterpret_cast<const f32x2*>(v4);

            #pragma unroll
            for (int jo = 0; jo < 4; ++jo) {
                f32x2 acc01; acc01.x = 0.f; acc01.y = 0.f;
                f32x2 acc23; acc23.x = 0.f; acc23.y = 0.f;
                #pragma unroll
                for (int k = 0; k < 11; ++k) {
                    const f32x2 g = {GW[k], GW[k]};
                    acc01 = __builtin_elementwise_fma(g, x01[jo + k], acc01);
                    acc23 = __builtin_elementwise_fma(g, x23[jo + k], acc23);
                }
                const float m1  = acc01.x;
                const float m2  = acc01.y;
                const float sPP = acc23.x;
                const float e12 = acc23.y;
                const float m1m2 = m1 * m2;
                const float msq  = fmaf(m1, m1, m2 * m2);
                const float num = fmaf(2.0f, m1m2, C1f) * fmaf(2.0f, (e12 - m1m2), C2f);
                const float den = (msq + C1f) * ((sPP - msq) + C2f);
                lsum = fmaf(num, __builtin_amdgcn_rcpf(den), lsum);
            }
        }
        __syncthreads();   // stats LDS reusable

        jm = (jm + 1 == NSLOT) ? 0 : jm + 1;
    }

    // ---------------- Reduction: wave shuffle -> LDS -> binned atomic ------
    #pragma unroll
    for (int off = 32; off > 0; off >>= 1) lsum += __shfl_down(lsum, off, 64);
    const int lane = tid & 63;
    const int wv   = tid >> 6;              // 0..4
    if (lane == 0) wsum[wv] = lsum;
    __syncthreads();
    if (tid == 0) {
        const float bs = wsum[0] + wsum[1] + wsum[2] + wsum[3] + wsum[4];
        atomicAdd(&ws[bid & (NBINS - 1)], bs);
    }
}

extern "C" void kernel_launch(void* const* d_in, const int* in_sizes, int n_in,
                              void* d_out, int out_size, void* d_ws, size_t ws_size,
                              hipStream_t stream) {
    const float* pred = (const float*)d_in[0];
    const float* targ = (const float*)d_in[1];
    float* out = (float*)d_out;
    float* wsf = (float*)d_ws;

    hipLaunchKernelGGL(ssim_zero, dim3(1), dim3(NBINS), 0, stream, wsf);
    hipLaunchKernelGGL(ssim_main, dim3(NBLK), dim3(NTHR), 0, stream, pred, targ, wsf);
    hipLaunchKernelGGL(ssim_fin, dim3(1), dim3(64), 0, stream, wsf, out);
}

// Round 8
// 167.081 us; speedup vs baseline: 1.0758x; 1.0687x over previous
//
#include <hip/hip_runtime.h>

// SSIM loss, fused separable Gaussian (11x11, sigma=1.5) over [32,3,512,512] f32.
// R8 = R5 skeleton with the two identified defects fixed:
//  (a) 320 threads: V-phase covers all 266 FIR cols in ONE pass (R5's tid<10
//      second iteration serialized the whole block at the barrier).
//  (b) sched_barrier(0) between the 28-load batch and the FIR: stops the
//      scheduler from sinking loads into uses (R5: VGPR=36, fully serialized
//      load->wait->use chains; now all 28 loads in flight -> one latency/tile).
//  (c) single uniform path: med3-clamped row addresses + row masks everywhere.
//  (d) bijective XCD swizzle: 128 vertically-consecutive tiles (sharing halo
//      rows) -> same XCD's L2 -> vertical re-reads become L2 hits.

typedef float f32x2 __attribute__((ext_vector_type(2)));

#define IH 512
#define IW 512
#define TH 4                 // output rows per tile
#define TW 256               // output cols per tile
#define PW 266               // TW + 10 FIR cols
#define RRN 14               // raw rows per tile
#define LPW 268              // stats row stride in f32x2
#define HTILES 128
#define NTILE 24576          // 96 images * 128 ht * 2 wt
#define CPX 3072             // NTILE / 8 XCDs (exact -> bijective)
#define NBINS 64
#define NPIX 25165824.0f     // 96*512*512
#define NTHR 320

constexpr float GW[11] = {
    0.00102838f, 0.00759877f, 0.03600078f, 0.10936070f, 0.21300554f,
    0.26601173f,
    0.21300554f, 0.10936070f, 0.03600078f, 0.00759877f, 0.00102838f
};
constexpr float C1f = 0.0001f;  // 0.01^2
constexpr float C2f = 0.0009f;  // 0.03^2

__global__ void ssim_zero(float* ws) { ws[threadIdx.x] = 0.0f; }

__global__ void ssim_fin(const float* __restrict__ ws, float* __restrict__ out) {
    float v = ws[threadIdx.x];
    #pragma unroll
    for (int off = 32; off > 0; off >>= 1) v += __shfl_down(v, off, 64);
    if (threadIdx.x == 0) out[0] = 1.0f - v * (1.0f / NPIX);
}

__global__ __launch_bounds__(NTHR, 2) void ssim_main(
    const float* __restrict__ pred,
    const float* __restrict__ targ,
    float* __restrict__ ws)
{
    __shared__ __align__(16) f32x2 lds01[TH][LPW];   // (E[p], E[t])
    __shared__ __align__(16) f32x2 lds23[TH][LPW];   // (E[p^2+t^2], E[p*t])
    __shared__ float wsum[5];

    const int tid = threadIdx.x;

    // -------- XCD-aware bijective swizzle: tl-consecutive = same XCD -------
    const int b  = blockIdx.x;
    const int tl = (b & 7) * CPX + (b >> 3);     // tile-linear
    const int ht = tl & (HTILES - 1);            // consecutive ht share rows
    const int wt = (tl >> 7) & 1;
    const int bc = tl >> 8;

    const int rbase = ht * TH - 5;
    const float* __restrict__ P = pred + (size_t)bc * (IH * IW);
    const float* __restrict__ T = targ + (size_t)bc * (IH * IW);

    // ---------------- V-phase: batched loads + vertical FIR ----------------
    if (tid < PW) {
        const int w = wt * TW - 5 + tid;
        const float wm = ((unsigned)w < (unsigned)IW) ? 1.0f : 0.0f;
        const int wc = w < 0 ? 0 : (w > IW - 1 ? IW - 1 : w);

        // row masks + clamped 32-bit element offsets
        float rm[RRN];
        int off[RRN];
        #pragma unroll
        for (int rr = 0; rr < RRN; ++rr) {
            const int h = rbase + rr;
            rm[rr] = ((unsigned)h < (unsigned)IH) ? 1.0f : 0.0f;
            const int hc = h < 0 ? 0 : (h > IH - 1 ? IH - 1 : h);
            off[rr] = hc * IW + wc;
        }

        // batched loads -> registers (sched_barrier keeps them batched)
        float pv[RRN], tv[RRN];
        #pragma unroll
        for (int rr = 0; rr < RRN; ++rr) pv[rr] = P[off[rr]];
        #pragma unroll
        for (int rr = 0; rr < RRN; ++rr) tv[rr] = T[off[rr]];
        __builtin_amdgcn_sched_barrier(0);

        f32x2 a01[TH], a23[TH];
        #pragma unroll
        for (int ro = 0; ro < TH; ++ro) {
            a01[ro].x = 0.f; a01[ro].y = 0.f;
            a23[ro].x = 0.f; a23[ro].y = 0.f;
        }

        #pragma unroll
        for (int rr = 0; rr < RRN; ++rr) {
            f32x2 s01; s01.x = pv[rr]; s01.y = tv[rr];
            const f32x2 rmv = {rm[rr], rm[rr]};
            s01 = s01 * rmv;                                  // border mask
            f32x2 s23;
            s23.x = fmaf(s01.x, s01.x, s01.y * s01.y);        // p^2 + t^2
            s23.y = s01.x * s01.y;                            // p*t
            #pragma unroll
            for (int ro = 0; ro < TH; ++ro) {
                const int k = rr - ro;       // compile-time after unroll
                if (k >= 0 && k < 11) {
                    const f32x2 g = {GW[k], GW[k]};
                    a01[ro] = __builtin_elementwise_fma(g, s01, a01[ro]);
                    a23[ro] = __builtin_elementwise_fma(g, s23, a23[ro]);
                }
            }
        }
        const f32x2 wmv = {wm, wm};
        #pragma unroll
        for (int ro = 0; ro < TH; ++ro) {
            lds01[ro][tid] = a01[ro] * wmv;
            lds23[ro][tid] = a23[ro] * wmv;
        }
    }
    __syncthreads();

    // ---------------- H-phase: horizontal conv + SSIM epilogue -------------
    float lsum = 0.0f;
    if (tid < 256) {
        const int r  = tid >> 6;            // 0..3
        const int c0 = (tid & 63) << 2;     // 0..252

        float4 u4[7], v4[7];
        const float4* b01 = reinterpret_cast<const float4*>(&lds01[r][c0]);
        const float4* b23 = reinterpret_cast<const float4*>(&lds23[r][c0]);
        #pragma unroll
        for (int q = 0; q < 7; ++q) { u4[q] = b01[q]; v4[q] = b23[q]; }
        const f32x2* x01 = reinterpret_cast<const f32x2*>(u4);   // 14 elems
        const f32x2* x23 = reinterpret_cast<const f32x2*>(v4);

        #pragma unroll
        for (int j = 0; j < 4; ++j) {
            f32x2 acc01; acc01.x = 0.f; acc01.y = 0.f;
            f32x2 acc23; acc23.x = 0.f; acc23.y = 0.f;
            #pragma unroll
            for (int k = 0; k < 11; ++k) {
                const f32x2 g = {GW[k], GW[k]};
                acc01 = __builtin_elementwise_fma(g, x01[j + k], acc01);
                acc23 = __builtin_elementwise_fma(g, x23[j + k], acc23);
            }
            const float m1  = acc01.x;
            const float m2  = acc01.y;
            const float sPP = acc23.x;      // E[p^2]+E[t^2]
            const float e12 = acc23.y;      // E[p*t]
            const float m1m2 = m1 * m2;
            const float msq  = fmaf(m1, m1, m2 * m2);
            const float num = fmaf(2.0f, m1m2, C1f) * fmaf(2.0f, (e12 - m1m2), C2f);
            const float den = (msq + C1f) * ((sPP - msq) + C2f);
            lsum = fmaf(num, __builtin_amdgcn_rcpf(den), lsum);
        }
    }

    // ---------------- Reduction: wave shuffle -> LDS -> binned atomic ------
    #pragma unroll
    for (int off = 32; off > 0; off >>= 1) lsum += __shfl_down(lsum, off, 64);
    const int lane = tid & 63;
    const int wv   = tid >> 6;              // 0..4
    if (lane == 0) wsum[wv] = lsum;
    __syncthreads();
    if (tid == 0) {
        const float bs = wsum[0] + wsum[1] + wsum[2] + wsum[3] + wsum[4];
        atomicAdd(&ws[b & (NBINS - 1)], bs);
    }
}

extern "C" void kernel_launch(void* const* d_in, const int* in_sizes, int n_in,
                              void* d_out, int out_size, void* d_ws, size_t ws_size,
                              hipStream_t stream) {
    const float* pred = (const float*)d_in[0];
    const float* targ = (const float*)d_in[1];
    float* out = (float*)d_out;
    float* wsf = (float*)d_ws;

    hipLaunchKernelGGL(ssim_zero, dim3(1), dim3(NBINS), 0, stream, wsf);
    hipLaunchKernelGGL(ssim_main, dim3(NTILE), dim3(NTHR), 0, stream, pred, targ, wsf);
    hipLaunchKernelGGL(ssim_fin, dim3(1), dim3(64), 0, stream, wsf, out);
}